// Round 12
// baseline (166.114 us; speedup 1.0000x reference)
//
#include <hip/hip_runtime.h>

#define NF 32       // IN_FEATS == OUT_FEATS == 32
#define RB 256      // nodes per bucket -> 391 buckets (R9-proven geometry)
#define RBITS 8
#define CAPE 5632   // per-bucket edge capacity (mean 4096, sigma 64, +24 sigma slack)
#define P1T 512     // partition threads
#define P1E 8       // edges per thread (tile = 4096 -> 391 blocks)
#define PT 512      // place threads
#define PE (CAPE / PT)  // 11 edges per thread
#define NBMAX 512   // >= nb
#define GT 256      // gather threads: 8 groups x 32 lanes
#define GB 2048     // gather blocks: 8/CU -> 32 waves/CU, persistent grid-stride

typedef _Float16 half8v __attribute__((ext_vector_type(8)));  // 16 B

// ---- Pass 1: bucket-partition edges by dst>>RBITS into ebuf (packed ldst<<17 | src) ----
// LDS histogram gives each edge a local rank; ONE global atomic per bucket reserves a
// contiguous run; writes land in ~40B runs that stay in L2 and merge into full lines.
__global__ __launch_bounds__(P1T) void partition_kernel(
    const int* __restrict__ src, const int* __restrict__ dst,
    int* __restrict__ gcount, unsigned int* __restrict__ ebuf, int n_edges, int nb) {
    __shared__ int hist[NBMAX];
    __shared__ int gbase[NBMAX];
    int t = threadIdx.x;
    hist[t] = 0;  // P1T == NBMAX == 512
    __syncthreads();
    int tile0 = blockIdx.x * (P1T * P1E);
    unsigned int pk[P1E];
    int br[P1E];
#pragma unroll
    for (int k = 0; k < P1E; k++) {
        int i = tile0 + k * P1T + t;
        int b = -1, r = 0;
        unsigned int p = 0;
        if (i < n_edges) {
            int d = dst[i];
            int s = src[i];
            b = d >> RBITS;
            p = ((unsigned int)(d & (RB - 1)) << 17) | (unsigned int)s;  // src < 2^17
            r = atomicAdd(&hist[b], 1);  // LDS atomic: local rank
        }
        pk[k] = p;
        br[k] = (b << 16) | r;  // b==-1 stays negative after >>16 (r < 4096 fits 16 bits)
    }
    __syncthreads();
    if (t < nb) gbase[t] = atomicAdd(&gcount[t], hist[t]);  // one global atomic per bucket
    __syncthreads();
#pragma unroll
    for (int k = 0; k < P1E; k++) {
        int b = br[k] >> 16;
        if (b >= 0) {
            int u = gbase[b] + (br[k] & 0xFFFF);
            if (u < CAPE) ebuf[(size_t)b * CAPE + u] = pk[k];  // guard: memory-safe on overflow
        }
    }
}

// ---- Pass 2: per-bucket counting sort -> csrc at FIXED stride b*CAPE, rowinfo =
// (beg, cnt), PLUS pre-projection h = (x*isd) @ W^T cast to fp16 (64 B rows).
// Aggregation is linear so projecting BEFORE aggregation is exact; it moves the
// 32x32 matmul out of the latency-critical gather into this throughput kernel.
// Block 0 zeroes the sentinel row h[n_nodes].
__global__ __launch_bounds__(PT) void place_kernel(
    const int* __restrict__ gcount, const unsigned int* __restrict__ ebuf,
    const float* __restrict__ x, const float* __restrict__ W,
    _Float16* __restrict__ hp, int* __restrict__ csrc, int2* __restrict__ rowinfo,
    int n_nodes, int nb) {
    __shared__ int hist[RB];        // per-node counts (= deg)
    __shared__ int lofs[RB];        // inclusive scan of counts
    __shared__ int sorted[CAPE];    // 22.5 KB staging
    __shared__ float sWt[NF * NF];  // sWt[i*32+o] = W[o*32+i]
    int t = threadIdx.x;
    int b = blockIdx.x;

    for (int k = t; k < NF * NF; k += PT) sWt[k] = W[(k & 31) * NF + (k >> 5)];
    if (t < RB) hist[t] = 0;
    // sentinel zero row (fp16 zeros == zero bits); workspace is re-poisoned each launch
    if (b == 0 && t < 16) ((float*)hp)[(size_t)n_nodes * 16 + t] = 0.f;
    __syncthreads();
    int c = min(gcount[b], CAPE);
    int base = b * CAPE;

    const unsigned int* eb = ebuf + (size_t)b * CAPE;
    unsigned int pk[PE];
    int pr[PE];
#pragma unroll
    for (int k = 0; k < PE; k++) {  // coalesced load + local rank per node
        int i = k * PT + t;
        unsigned int p = 0;
        int r = -1;
        if (i < c) {
            p = eb[i];
            r = atomicAdd(&hist[p >> 17], 1);
        }
        pk[k] = p;
        pr[k] = r;
    }
    __syncthreads();
    if (t < RB) lofs[t] = hist[t];
    __syncthreads();
    for (int d = 1; d < RB; d <<= 1) {  // inclusive scan of per-node counts
        int y = 0;
        if (t < RB && t >= d) y = lofs[t - d];
        __syncthreads();
        if (t < RB) lofs[t] += y;
        __syncthreads();
    }
#pragma unroll
    for (int k = 0; k < PE; k++) {  // scatter to per-node-sorted order in LDS
        if (pr[k] >= 0) {
            int ld = (int)(pk[k] >> 17);
            sorted[lofs[ld] - hist[ld] + pr[k]] = (int)(pk[k] & 0x1FFFF);
        }
    }
    __syncthreads();
    for (int i = t; i < c; i += PT) csrc[base + i] = sorted[i];  // coalesced out
    if (t < RB) {
        int node = (b << RBITS) + t;
        if (node < n_nodes) rowinfo[node] = make_int2(base + lofs[t] - hist[t], hist[t]);
    }
    // fused pre-projection: h[node] = (fp16)( si * (x[node] @ W^T) ), si = rsqrt(deg+1).
    // hist[] is read-only since the rank-phase barrier; 16 groups x 32 lanes; x-row
    // reads are lane-uniform broadcasts (L1-served).
    int o = t & 31;
    int ng = t >> 5;
    for (int ld = ng; ld < RB; ld += 16) {
        int node = (b << RBITS) + ld;
        if (node < n_nodes) {
            float si = rsqrtf((float)(hist[ld] + 1));
            const float* xr = x + (size_t)node * NF;
            float acc = 0.f;
#pragma unroll
            for (int i = 0; i < NF; i++) acc = fmaf(xr[i], sWt[i * NF + o], acc);
            hp[(size_t)node * NF + o] = (_Float16)(acc * si);
        }
    }
}

// ---- Pass 3: persistent gather with 3-deep modulo-scheduled pipeline ------------------
// 2048 blocks x 256 thr = 8 blocks/CU (32 waves/CU), zero LDS. 32-lane group =
// 8 edge-slots x 4 f-slots. Iteration k issues: rowinfo[n+3] | csrc-chunk[n+2]
// (rowinfo landed last iter) | hp-loads[n+1] (idx landed last iter), then accumulates
// node n from hp loads issued LAST iteration -> every dependent load gets a full
// iteration to land; hp misses for n+1 hide under n's accumulate+fold+store.
// Register economy (target <=64 VGPR, 8 waves/SIMD): bias + self-loop row loaded at
// fold time (L1-hot), two w-sets only.
__global__ __launch_bounds__(GT, 8) void gather_h(
    const int2* __restrict__ rowinfo, const int* __restrict__ csrc,
    const half8v* __restrict__ hp, const float* __restrict__ bias,
    float* __restrict__ out, int n_nodes) {
    int t = threadIdx.x;
    int g = t >> 5, o = t & 31;
    int q = o >> 2;  // edge slot within the stride (0..7)
    int f = o & 3;   // 16 B slot within a row (0..3)
    const int STR = GB * (GT / 32);
    int node = blockIdx.x * (GT / 32) + g;
    if (node >= n_nodes) return;

    // ---- prologue: fill the 3-deep pipeline (serial chains, once) ----
    int2 riC = rowinfo[node];
    int idxC = (o < riC.y) ? csrc[riC.x + o] : n_nodes;
    int e0 = __shfl(idxC, q, 32), e1 = __shfl(idxC, 8 + q, 32);
    int e2 = __shfl(idxC, 16 + q, 32), e3 = __shfl(idxC, 24 + q, 32);
    half8v wc0 = hp[(size_t)e0 * 4 + f], wc1 = hp[(size_t)e1 * 4 + f];
    half8v wc2 = hp[(size_t)e2 * 4 + f], wc3 = hp[(size_t)e3 * 4 + f];
    bool haveN = (node + STR) < n_nodes;
    int2 riN = haveN ? rowinfo[node + STR] : make_int2(0, 0);
    int idxN = (haveN && o < riN.y) ? csrc[riN.x + o] : n_nodes;
    int2 ri2 = ((node + 2 * STR) < n_nodes) ? rowinfo[node + 2 * STR] : make_int2(0, 0);

    while (true) {
        // step 1: issue hp loads for node n+1 (idxN landed: issued last iteration)
        half8v wn0, wn1, wn2, wn3;
        if (haveN) {
            int x0 = __shfl(idxN, q, 32), x1 = __shfl(idxN, 8 + q, 32);
            int x2 = __shfl(idxN, 16 + q, 32), x3 = __shfl(idxN, 24 + q, 32);
            wn0 = hp[(size_t)x0 * 4 + f]; wn1 = hp[(size_t)x1 * 4 + f];
            wn2 = hp[(size_t)x2 * 4 + f]; wn3 = hp[(size_t)x3 * 4 + f];
        }
        // step 2: issue csrc chunk for node n+2 (ri2 landed: issued last iteration)
        int idx2 = n_nodes;
        if ((node + 2 * STR) < n_nodes) idx2 = (o < ri2.y) ? csrc[ri2.x + o] : n_nodes;
        // step 3: issue rowinfo for node n+3
        int2 ri3 = ((node + 3 * STR) < n_nodes) ? rowinfo[node + 3 * STR]
                                                : make_int2(0, 0);
        // step 4: accumulate current node from wc* (issued last iteration)
        int cnt = riC.y;
        float a0, a1, a2, a3, a4, a5, a6, a7;
        a0 = (float)wc0[0] + (float)wc1[0] + (float)wc2[0] + (float)wc3[0];
        a1 = (float)wc0[1] + (float)wc1[1] + (float)wc2[1] + (float)wc3[1];
        a2 = (float)wc0[2] + (float)wc1[2] + (float)wc2[2] + (float)wc3[2];
        a3 = (float)wc0[3] + (float)wc1[3] + (float)wc2[3] + (float)wc3[3];
        a4 = (float)wc0[4] + (float)wc1[4] + (float)wc2[4] + (float)wc3[4];
        a5 = (float)wc0[5] + (float)wc1[5] + (float)wc2[5] + (float)wc3[5];
        a6 = (float)wc0[6] + (float)wc1[6] + (float)wc2[6] + (float)wc3[6];
        a7 = (float)wc0[7] + (float)wc1[7] + (float)wc2[7] + (float)wc3[7];
        // step 5: rare tail (cnt > 32): inline chunks, sentinel-clamped
        for (int s = 32; s < cnt; s += 32) {
            int i = s + o;
            int idx = (i < cnt) ? csrc[riC.x + i] : n_nodes;
            int y0 = __shfl(idx, q, 32), y1 = __shfl(idx, 8 + q, 32);
            int y2 = __shfl(idx, 16 + q, 32), y3 = __shfl(idx, 24 + q, 32);
            half8v v0 = hp[(size_t)y0 * 4 + f], v1 = hp[(size_t)y1 * 4 + f];
            half8v v2 = hp[(size_t)y2 * 4 + f], v3 = hp[(size_t)y3 * 4 + f];
            a0 += (float)v0[0] + (float)v1[0] + (float)v2[0] + (float)v3[0];
            a1 += (float)v0[1] + (float)v1[1] + (float)v2[1] + (float)v3[1];
            a2 += (float)v0[2] + (float)v1[2] + (float)v2[2] + (float)v3[2];
            a3 += (float)v0[3] + (float)v1[3] + (float)v2[3] + (float)v3[3];
            a4 += (float)v0[4] + (float)v1[4] + (float)v2[4] + (float)v3[4];
            a5 += (float)v0[5] + (float)v1[5] + (float)v2[5] + (float)v3[5];
            a6 += (float)v0[6] + (float)v1[6] + (float)v2[6] + (float)v3[6];
            a7 += (float)v0[7] + (float)v1[7] + (float)v2[7] + (float)v3[7];
        }
        // step 6: fold the 8 edge-slots (lanes f, f+4, ..., f+28 share the same slot)
        a0 += __shfl_down(a0, 4, 32); a1 += __shfl_down(a1, 4, 32);
        a2 += __shfl_down(a2, 4, 32); a3 += __shfl_down(a3, 4, 32);
        a4 += __shfl_down(a4, 4, 32); a5 += __shfl_down(a5, 4, 32);
        a6 += __shfl_down(a6, 4, 32); a7 += __shfl_down(a7, 4, 32);
        a0 += __shfl_down(a0, 8, 32); a1 += __shfl_down(a1, 8, 32);
        a2 += __shfl_down(a2, 8, 32); a3 += __shfl_down(a3, 8, 32);
        a4 += __shfl_down(a4, 8, 32); a5 += __shfl_down(a5, 8, 32);
        a6 += __shfl_down(a6, 8, 32); a7 += __shfl_down(a7, 8, 32);
        a0 += __shfl_down(a0, 16, 32); a1 += __shfl_down(a1, 16, 32);
        a2 += __shfl_down(a2, 16, 32); a3 += __shfl_down(a3, 16, 32);
        a4 += __shfl_down(a4, 16, 32); a5 += __shfl_down(a5, 16, 32);
        a6 += __shfl_down(a6, 16, 32); a7 += __shfl_down(a7, 16, 32);
        // step 7: epilogue (lanes 0..3): self-loop row + bias loaded here (L1/L2-hot)
        if (q == 0) {
            float si = rsqrtf((float)(cnt + 1));
            half8v sv = hp[(size_t)node * 4 + f];
            const float* bp = bias + f * 8;
            float4 r1, r2;
            r1.x = fmaxf(fmaf(a0 + (float)sv[0], si, bp[0]), 0.f);
            r1.y = fmaxf(fmaf(a1 + (float)sv[1], si, bp[1]), 0.f);
            r1.z = fmaxf(fmaf(a2 + (float)sv[2], si, bp[2]), 0.f);
            r1.w = fmaxf(fmaf(a3 + (float)sv[3], si, bp[3]), 0.f);
            r2.x = fmaxf(fmaf(a4 + (float)sv[4], si, bp[4]), 0.f);
            r2.y = fmaxf(fmaf(a5 + (float)sv[5], si, bp[5]), 0.f);
            r2.z = fmaxf(fmaf(a6 + (float)sv[6], si, bp[6]), 0.f);
            r2.w = fmaxf(fmaf(a7 + (float)sv[7], si, bp[7]), 0.f);
            float4* o4 = (float4*)(out + (size_t)node * NF);
            o4[f * 2] = r1;
            o4[f * 2 + 1] = r2;
        }
        if (!haveN) break;
        // rotate the pipeline one stage
        node += STR;
        riC = riN;
        wc0 = wn0; wc1 = wn1; wc2 = wn2; wc3 = wn3;
        riN = ri2; idxN = idx2; ri2 = ri3;
        haveN = (node + STR) < n_nodes;
    }
}

extern "C" void kernel_launch(void* const* d_in, const int* in_sizes, int n_in,
                              void* d_out, int out_size, void* d_ws, size_t ws_size,
                              hipStream_t stream) {
    const float* feature = (const float*)d_in[0];
    const int*   src     = (const int*)d_in[1];
    const int*   dst     = (const int*)d_in[2];
    const float* W       = (const float*)d_in[3];
    const float* bias    = (const float*)d_in[4];
    float* out = (float*)d_out;

    int n_nodes = in_sizes[0] / NF;
    int n_edges = in_sizes[1];
    int nb = (n_nodes + RB - 1) / RB;  // 391 buckets

    char* ws = (char*)d_ws;
    size_t off = 0;
    unsigned int* ebuf = (unsigned int*)(ws + off);
    off += (((size_t)nb * CAPE * 4) + 255) & ~(size_t)255;
    int* csrc = (int*)(ws + off);
    off += (((size_t)nb * CAPE * 4) + 255) & ~(size_t)255;
    int2* rowinfo = (int2*)(ws + off);
    off += ((size_t)n_nodes * 8 + 255) & ~(size_t)255;
    _Float16* hp = (_Float16*)(ws + off);
    off += ((size_t)(n_nodes + 1) * NF * 2 + 255) & ~(size_t)255;  // +1 sentinel zero row
    int* gcount = (int*)(ws + off);

    hipMemsetAsync(gcount, 0, NBMAX * 4, stream);

    int p1_grid = (n_edges + P1T * P1E - 1) / (P1T * P1E);
    partition_kernel<<<p1_grid, P1T, 0, stream>>>(src, dst, gcount, ebuf, n_edges, nb);

    place_kernel<<<nb, PT, 0, stream>>>(gcount, ebuf, feature, W, hp, csrc, rowinfo,
                                        n_nodes, nb);

    gather_h<<<GB, GT, 0, stream>>>(rowinfo, csrc, (const half8v*)hp, bias, out, n_nodes);
}

// Round 13
// 143.117 us; speedup vs baseline: 1.1607x; 1.1607x over previous
//
#include <hip/hip_runtime.h>

#define NF 32       // IN_FEATS == OUT_FEATS == 32
#define RB 256      // nodes per bucket -> 391 buckets (R9-proven geometry)
#define RBITS 8
#define CAPE 5632   // per-bucket edge capacity (mean 4096, sigma 64, +24 sigma slack)
#define P1T 512     // partition threads
#define P1E 8       // edges per thread (tile = 4096 -> 391 blocks)
#define PT 512      // place threads
#define PE (CAPE / PT)  // 11 edges per thread
#define NBMAX 512   // >= nb
#define GT 256      // gather threads: 8 groups x 32 lanes
#define GB 2048     // gather blocks: 8/CU available, persistent grid-stride

typedef _Float16 half8v __attribute__((ext_vector_type(8)));  // 16 B

// ---- Pass 1: bucket-partition edges by dst>>RBITS into ebuf (packed ldst<<17 | src) ----
// LDS histogram gives each edge a local rank; ONE global atomic per bucket reserves a
// contiguous run; writes land in ~40B runs that stay in L2 and merge into full lines.
__global__ __launch_bounds__(P1T) void partition_kernel(
    const int* __restrict__ src, const int* __restrict__ dst,
    int* __restrict__ gcount, unsigned int* __restrict__ ebuf, int n_edges, int nb) {
    __shared__ int hist[NBMAX];
    __shared__ int gbase[NBMAX];
    int t = threadIdx.x;
    hist[t] = 0;  // P1T == NBMAX == 512
    __syncthreads();
    int tile0 = blockIdx.x * (P1T * P1E);
    unsigned int pk[P1E];
    int br[P1E];
#pragma unroll
    for (int k = 0; k < P1E; k++) {
        int i = tile0 + k * P1T + t;
        int b = -1, r = 0;
        unsigned int p = 0;
        if (i < n_edges) {
            int d = dst[i];
            int s = src[i];
            b = d >> RBITS;
            p = ((unsigned int)(d & (RB - 1)) << 17) | (unsigned int)s;  // src < 2^17
            r = atomicAdd(&hist[b], 1);  // LDS atomic: local rank
        }
        pk[k] = p;
        br[k] = (b << 16) | r;  // b==-1 stays negative after >>16 (r < 4096 fits 16 bits)
    }
    __syncthreads();
    if (t < nb) gbase[t] = atomicAdd(&gcount[t], hist[t]);  // one global atomic per bucket
    __syncthreads();
#pragma unroll
    for (int k = 0; k < P1E; k++) {
        int b = br[k] >> 16;
        if (b >= 0) {
            int u = gbase[b] + (br[k] & 0xFFFF);
            if (u < CAPE) ebuf[(size_t)b * CAPE + u] = pk[k];  // guard: memory-safe on overflow
        }
    }
}

// ---- Pass 2: per-bucket counting sort -> csrc at FIXED stride b*CAPE, rowinfo =
// (beg, cnt), PLUS pre-projection h = (x*isd) @ W^T cast to fp16 (64 B rows).
// Aggregation is linear so projecting BEFORE aggregation is exact; it moves the
// 32x32 matmul out of the latency-critical gather into this throughput kernel.
// Block 0 zeroes the sentinel row h[n_nodes].
__global__ __launch_bounds__(PT) void place_kernel(
    const int* __restrict__ gcount, const unsigned int* __restrict__ ebuf,
    const float* __restrict__ x, const float* __restrict__ W,
    _Float16* __restrict__ hp, int* __restrict__ csrc, int2* __restrict__ rowinfo,
    int n_nodes, int nb) {
    __shared__ int hist[RB];        // per-node counts (= deg)
    __shared__ int lofs[RB];        // inclusive scan of counts
    __shared__ int sorted[CAPE];    // 22.5 KB staging
    __shared__ float sWt[NF * NF];  // sWt[i*32+o] = W[o*32+i]
    int t = threadIdx.x;
    int b = blockIdx.x;

    for (int k = t; k < NF * NF; k += PT) sWt[k] = W[(k & 31) * NF + (k >> 5)];
    if (t < RB) hist[t] = 0;
    // sentinel zero row (fp16 zeros == zero bits); workspace is re-poisoned each launch
    if (b == 0 && t < 16) ((float*)hp)[(size_t)n_nodes * 16 + t] = 0.f;
    __syncthreads();
    int c = min(gcount[b], CAPE);
    int base = b * CAPE;

    const unsigned int* eb = ebuf + (size_t)b * CAPE;
    unsigned int pk[PE];
    int pr[PE];
#pragma unroll
    for (int k = 0; k < PE; k++) {  // coalesced load + local rank per node
        int i = k * PT + t;
        unsigned int p = 0;
        int r = -1;
        if (i < c) {
            p = eb[i];
            r = atomicAdd(&hist[p >> 17], 1);
        }
        pk[k] = p;
        pr[k] = r;
    }
    __syncthreads();
    if (t < RB) lofs[t] = hist[t];
    __syncthreads();
    for (int d = 1; d < RB; d <<= 1) {  // inclusive scan of per-node counts
        int y = 0;
        if (t < RB && t >= d) y = lofs[t - d];
        __syncthreads();
        if (t < RB) lofs[t] += y;
        __syncthreads();
    }
#pragma unroll
    for (int k = 0; k < PE; k++) {  // scatter to per-node-sorted order in LDS
        if (pr[k] >= 0) {
            int ld = (int)(pk[k] >> 17);
            sorted[lofs[ld] - hist[ld] + pr[k]] = (int)(pk[k] & 0x1FFFF);
        }
    }
    __syncthreads();
    for (int i = t; i < c; i += PT) csrc[base + i] = sorted[i];  // coalesced out
    if (t < RB) {
        int node = (b << RBITS) + t;
        if (node < n_nodes) rowinfo[node] = make_int2(base + lofs[t] - hist[t], hist[t]);
    }
    // fused pre-projection: h[node] = (fp16)( si * (x[node] @ W^T) ), si = rsqrt(deg+1).
    // hist[] is read-only since the rank-phase barrier; 16 groups x 32 lanes; x-row
    // reads are lane-uniform broadcasts (L1-served).
    int o = t & 31;
    int ng = t >> 5;
    for (int ld = ng; ld < RB; ld += 16) {
        int node = (b << RBITS) + ld;
        if (node < n_nodes) {
            float si = rsqrtf((float)(hist[ld] + 1));
            const float* xr = x + (size_t)node * NF;
            float acc = 0.f;
#pragma unroll
            for (int i = 0; i < NF; i++) acc = fmaf(xr[i], sWt[i * NF + o], acc);
            hp[(size_t)node * NF + o] = (_Float16)(acc * si);
        }
    }
}

// ---- Pass 3: persistent gather, 2-deep cross-node prefetch, NATURAL regalloc ----------
// 2048 blocks x 256 thr, persistent grid-stride, zero LDS, NO forced min-occupancy
// (R12's __launch_bounds__(GT,8) caused 100 MB of scratch spill traffic).
// 32-lane group = 8 edge-slots x 4 f-slots; 4 independent dwordx4 per 32-edge chunk.
// Cross-node pipeline: next node's rowinfo AND first csrc chunk prefetched so their
// dependent-load latency hides under the current node's accumulate/fold/store.
// Epilogue is fold + relu(fma) + two float4 stores (projection already in hp).
__global__ __launch_bounds__(GT) void gather_h(
    const int2* __restrict__ rowinfo, const int* __restrict__ csrc,
    const half8v* __restrict__ hp, const float* __restrict__ bias,
    float* __restrict__ out, int n_nodes) {
    int t = threadIdx.x;
    int g = t >> 5, o = t & 31;
    int q = o >> 2;  // edge slot within the stride (0..7)
    int f = o & 3;   // 16 B slot within a row (0..3)
    const int STR = GB * (GT / 32);
    int node = blockIdx.x * (GT / 32) + g;
    if (node >= n_nodes) return;
    int2 ri = rowinfo[node];
    int idx0 = (o < ri.y) ? csrc[ri.x + o] : n_nodes;  // first chunk, prefetched
    while (true) {
        int nnext = node + STR;
        bool have_next = nnext < n_nodes;
        int2 ri_next;
        if (have_next) ri_next = rowinfo[nnext];  // prefetch rowinfo for node n+1
        int beg = ri.x, cnt = ri.y;
        float a0 = 0.f, a1 = 0.f, a2 = 0.f, a3 = 0.f;
        float a4 = 0.f, a5 = 0.f, a6 = 0.f, a7 = 0.f;
        for (int s = 0; s < cnt; s += 32) {
            int idx;
            if (s == 0) {
                idx = idx0;  // preloaded during previous node's epilogue
            } else {
                int i = s + o;
                idx = (i < cnt) ? csrc[beg + i] : n_nodes;  // OOR -> sentinel zero row
            }
            int e0 = __shfl(idx, q, 32);
            int e1 = __shfl(idx, 8 + q, 32);
            int e2 = __shfl(idx, 16 + q, 32);
            int e3 = __shfl(idx, 24 + q, 32);
            half8v w0 = hp[(size_t)e0 * 4 + f];   // 4 independent dwordx4
            half8v w1 = hp[(size_t)e1 * 4 + f];
            half8v w2 = hp[(size_t)e2 * 4 + f];
            half8v w3 = hp[(size_t)e3 * 4 + f];
            a0 += (float)w0[0] + (float)w1[0] + (float)w2[0] + (float)w3[0];
            a1 += (float)w0[1] + (float)w1[1] + (float)w2[1] + (float)w3[1];
            a2 += (float)w0[2] + (float)w1[2] + (float)w2[2] + (float)w3[2];
            a3 += (float)w0[3] + (float)w1[3] + (float)w2[3] + (float)w3[3];
            a4 += (float)w0[4] + (float)w1[4] + (float)w2[4] + (float)w3[4];
            a5 += (float)w0[5] + (float)w1[5] + (float)w2[5] + (float)w3[5];
            a6 += (float)w0[6] + (float)w1[6] + (float)w2[6] + (float)w3[6];
            a7 += (float)w0[7] + (float)w1[7] + (float)w2[7] + (float)w3[7];
        }
        int idx0_next = 0;  // prefetch next node's first chunk under the fold/store
        if (have_next) idx0_next = (o < ri_next.y) ? csrc[ri_next.x + o] : n_nodes;
        // fold the 8 edge-slots (lanes f, f+4, ..., f+28 share the same 16 B slot)
        a0 += __shfl_down(a0, 4, 32); a1 += __shfl_down(a1, 4, 32);
        a2 += __shfl_down(a2, 4, 32); a3 += __shfl_down(a3, 4, 32);
        a4 += __shfl_down(a4, 4, 32); a5 += __shfl_down(a5, 4, 32);
        a6 += __shfl_down(a6, 4, 32); a7 += __shfl_down(a7, 4, 32);
        a0 += __shfl_down(a0, 8, 32); a1 += __shfl_down(a1, 8, 32);
        a2 += __shfl_down(a2, 8, 32); a3 += __shfl_down(a3, 8, 32);
        a4 += __shfl_down(a4, 8, 32); a5 += __shfl_down(a5, 8, 32);
        a6 += __shfl_down(a6, 8, 32); a7 += __shfl_down(a7, 8, 32);
        a0 += __shfl_down(a0, 16, 32); a1 += __shfl_down(a1, 16, 32);
        a2 += __shfl_down(a2, 16, 32); a3 += __shfl_down(a3, 16, 32);
        a4 += __shfl_down(a4, 16, 32); a5 += __shfl_down(a5, 16, 32);
        a6 += __shfl_down(a6, 16, 32); a7 += __shfl_down(a7, 16, 32);
        if (q == 0) {  // lanes 0..3 hold totals for features [f*8, f*8+8)
            float si = rsqrtf((float)(cnt + 1));
            half8v sv = hp[(size_t)node * 4 + f];  // self-loop h row (L2-hot)
            const float* bp = bias + f * 8;        // L1-resident
            float4 r1, r2;
            r1.x = fmaxf(fmaf(a0 + (float)sv[0], si, bp[0]), 0.f);
            r1.y = fmaxf(fmaf(a1 + (float)sv[1], si, bp[1]), 0.f);
            r1.z = fmaxf(fmaf(a2 + (float)sv[2], si, bp[2]), 0.f);
            r1.w = fmaxf(fmaf(a3 + (float)sv[3], si, bp[3]), 0.f);
            r2.x = fmaxf(fmaf(a4 + (float)sv[4], si, bp[4]), 0.f);
            r2.y = fmaxf(fmaf(a5 + (float)sv[5], si, bp[5]), 0.f);
            r2.z = fmaxf(fmaf(a6 + (float)sv[6], si, bp[6]), 0.f);
            r2.w = fmaxf(fmaf(a7 + (float)sv[7], si, bp[7]), 0.f);
            float4* o4 = (float4*)(out + (size_t)node * NF);
            o4[f * 2] = r1;
            o4[f * 2 + 1] = r2;
        }
        if (!have_next) break;
        node = nnext;
        ri = ri_next;
        idx0 = idx0_next;
    }
}

extern "C" void kernel_launch(void* const* d_in, const int* in_sizes, int n_in,
                              void* d_out, int out_size, void* d_ws, size_t ws_size,
                              hipStream_t stream) {
    const float* feature = (const float*)d_in[0];
    const int*   src     = (const int*)d_in[1];
    const int*   dst     = (const int*)d_in[2];
    const float* W       = (const float*)d_in[3];
    const float* bias    = (const float*)d_in[4];
    float* out = (float*)d_out;

    int n_nodes = in_sizes[0] / NF;
    int n_edges = in_sizes[1];
    int nb = (n_nodes + RB - 1) / RB;  // 391 buckets

    char* ws = (char*)d_ws;
    size_t off = 0;
    unsigned int* ebuf = (unsigned int*)(ws + off);
    off += (((size_t)nb * CAPE * 4) + 255) & ~(size_t)255;
    int* csrc = (int*)(ws + off);
    off += (((size_t)nb * CAPE * 4) + 255) & ~(size_t)255;
    int2* rowinfo = (int2*)(ws + off);
    off += ((size_t)n_nodes * 8 + 255) & ~(size_t)255;
    _Float16* hp = (_Float16*)(ws + off);
    off += ((size_t)(n_nodes + 1) * NF * 2 + 255) & ~(size_t)255;  // +1 sentinel zero row
    int* gcount = (int*)(ws + off);

    hipMemsetAsync(gcount, 0, NBMAX * 4, stream);

    int p1_grid = (n_edges + P1T * P1E - 1) / (P1T * P1E);
    partition_kernel<<<p1_grid, P1T, 0, stream>>>(src, dst, gcount, ebuf, n_edges, nb);

    place_kernel<<<nb, PT, 0, stream>>>(gcount, ebuf, feature, W, hp, csrc, rowinfo,
                                        n_nodes, nb);

    gather_h<<<GB, GT, 0, stream>>>(rowinfo, csrc, (const half8v*)hp, bias, out, n_nodes);
}